// Round 1
// baseline (9455.223 us; speedup 1.0000x reference)
//
#include <hip/hip_runtime.h>
#include <hip/hip_fp16.h>

#define B_   64
#define T_   512
#define DINc 512
#define D_   512
#define NWG  32
#define JS   16   // output columns per workgroup in scan

typedef _Float16 half8 __attribute__((ext_vector_type(8)));
typedef float   floatx4 __attribute__((ext_vector_type(4)));

// ---------------- X convert + transpose: Xh[m][k] = (f16) X[b][t][k], m = t*64+b ----------------
__global__ __launch_bounds__(256) void k_cvtX(const float* __restrict__ X, _Float16* __restrict__ Xh) {
    int idx = blockIdx.x * 256 + threadIdx.x;        // over 32768*64 groups of 8
    int m  = idx >> 6;
    int k8 = idx & 63;
    int b = m & 63, t = m >> 6;
    const float* src = X + ((size_t)(b * T_ + t)) * DINc + k8 * 8;
    float4 f0 = *(const float4*)(src);
    float4 f1 = *(const float4*)(src + 4);
    half8 h;
    h[0] = (_Float16)f0.x; h[1] = (_Float16)f0.y; h[2] = (_Float16)f0.z; h[3] = (_Float16)f0.w;
    h[4] = (_Float16)f1.x; h[5] = (_Float16)f1.y; h[6] = (_Float16)f1.z; h[7] = (_Float16)f1.w;
    *(half8*)(Xh + (size_t)m * DINc + k8 * 8) = h;
}

// ---------------- W transpose + convert: Wt[g][n][k] = (f16) W_g[k][n] ----------------
__global__ __launch_bounds__(256) void k_cvtW(const float* __restrict__ Wz, const float* __restrict__ Wr,
                                              const float* __restrict__ Wh, _Float16* __restrict__ Wt) {
    __shared__ float tile[64][65];
    int g = blockIdx.z;
    const float* W = (g == 0) ? Wz : ((g == 1) ? Wr : Wh);
    int n0 = blockIdx.x * 64, k0 = blockIdx.y * 64;
    int c = threadIdx.x & 63, r4 = threadIdx.x >> 6;
#pragma unroll
    for (int i = 0; i < 16; ++i) {
        int k = r4 + i * 4;
        tile[k][c] = W[(size_t)(k0 + k) * D_ + n0 + c];
    }
    __syncthreads();
    _Float16* out = Wt + (size_t)g * D_ * DINc;
#pragma unroll
    for (int i = 0; i < 16; ++i) {
        int n = r4 + i * 4;
        out[(size_t)(n0 + n) * DINc + k0 + c] = (_Float16)tile[c][n];
    }
}

// ---------------- input projections: xproj[g][m][n] = Xh[m][:] @ W_g[:][n] + b_g[n]  (f16 out) ----------------
__global__ __launch_bounds__(256) void k_gemm(const _Float16* __restrict__ Xh, const _Float16* __restrict__ Wt,
                                              const float* __restrict__ bz, const float* __restrict__ br,
                                              const float* __restrict__ bh, _Float16* __restrict__ xproj) {
    __shared__ _Float16 As[128 * 32];
    __shared__ _Float16 Bs[128 * 32];
    int g = blockIdx.z;
    const _Float16* Wg = Wt + (size_t)g * 512 * 512;
    const float* bias = (g == 0) ? bz : ((g == 1) ? br : bh);
    _Float16* out = xproj + (size_t)g * 32768 * 512;
    int mb = blockIdx.x * 128, nb = blockIdx.y * 128;
    int tid = threadIdx.x, l = tid & 63, w = tid >> 6;
    int wr = w >> 1, wc = w & 1;
    int lr = l & 15, lg = l >> 4;

    floatx4 acc[4][4] = {};

    int ga0 = tid, ga1 = tid + 256;       // 16B granules: row = ga>>2, gcol = ga&3
    int ra0 = ga0 >> 2, ca0 = (ga0 & 3) * 8;
    int ra1 = ga1 >> 2, ca1 = (ga1 & 3) * 8;

    uint4 pa0, pa1, pb0, pb1;
    pa0 = *(const uint4*)(Xh + (size_t)(mb + ra0) * 512 + ca0);
    pa1 = *(const uint4*)(Xh + (size_t)(mb + ra1) * 512 + ca1);
    pb0 = *(const uint4*)(Wg + (size_t)(nb + ra0) * 512 + ca0);
    pb1 = *(const uint4*)(Wg + (size_t)(nb + ra1) * 512 + ca1);

    for (int kt = 0; kt < 16; ++kt) {
        __syncthreads();
        *(uint4*)(&As[ga0 * 8]) = pa0;
        *(uint4*)(&As[ga1 * 8]) = pa1;
        *(uint4*)(&Bs[ga0 * 8]) = pb0;
        *(uint4*)(&Bs[ga1 * 8]) = pb1;
        __syncthreads();
        if (kt < 15) {
            int kb = (kt + 1) * 32;
            pa0 = *(const uint4*)(Xh + (size_t)(mb + ra0) * 512 + kb + ca0);
            pa1 = *(const uint4*)(Xh + (size_t)(mb + ra1) * 512 + kb + ca1);
            pb0 = *(const uint4*)(Wg + (size_t)(nb + ra0) * 512 + kb + ca0);
            pb1 = *(const uint4*)(Wg + (size_t)(nb + ra1) * 512 + kb + ca1);
        }
        half8 af[4], bf[4];
#pragma unroll
        for (int mi = 0; mi < 4; mi++) af[mi] = *(const half8*)(&As[(wr * 64 + mi * 16 + lr) * 32 + lg * 8]);
#pragma unroll
        for (int ni = 0; ni < 4; ni++) bf[ni] = *(const half8*)(&Bs[(wc * 64 + ni * 16 + lr) * 32 + lg * 8]);
#pragma unroll
        for (int mi = 0; mi < 4; mi++)
#pragma unroll
            for (int ni = 0; ni < 4; ni++)
                acc[mi][ni] = __builtin_amdgcn_mfma_f32_16x16x32_f16(af[mi], bf[ni], acc[mi][ni], 0, 0, 0);
    }

#pragma unroll
    for (int ni = 0; ni < 4; ni++) {
        int col = nb + wc * 64 + ni * 16 + lr;
        float bv = bias[col];
#pragma unroll
        for (int mi = 0; mi < 4; mi++) {
            int row = mb + wr * 64 + mi * 16 + lg * 4;
#pragma unroll
            for (int i = 0; i < 4; i++)
                out[(size_t)(row + i) * 512 + col] = (_Float16)(acc[mi][ni][i] + bv);
        }
    }
}

// ---------------- recurrent scan: 32 persistent WGs, each owns JS=16 columns ----------------
__global__ __launch_bounds__(256) void k_scan(const float* __restrict__ Uz, const float* __restrict__ Ur,
                                              const float* __restrict__ Uh, const int* __restrict__ mask,
                                              const _Float16* __restrict__ xproj,
                                              _Float16* __restrict__ hmbuf,   // [2][64][512] f16
                                              _Float16* __restrict__ rhbuf,   // [2][64][512] f16
                                              unsigned int* __restrict__ flags,
                                              float* __restrict__ out) {
    __shared__ _Float16 Ulds[3 * JS * 512];   // 48KB: gate-major, transposed [n][k], XOR-swizzled
    int tid = threadIdx.x, l = tid & 63, w = tid >> 6;
    int lr = l & 15, lg = l >> 4;
    int wg = blockIdx.x;
    int jsb = wg * JS;

    // ---- stage U slices into LDS (transposed + swizzled), fp32 -> fp16 ----
    {
        const float* Us0 = Uz; const float* Us1 = Ur; const float* Us2 = Uh;
        for (int idx = tid; idx < JS * 512; idx += 256) {
            int n = idx & (JS - 1);
            int k = idx >> 4;
            int byte_off = n * 1024 + (((k * 2)) ^ ((n & 7) << 4));
            *(_Float16*)((char*)Ulds + byte_off)                 = (_Float16)Us0[(size_t)k * D_ + jsb + n];
            *(_Float16*)((char*)Ulds + 16384 + byte_off)         = (_Float16)Us1[(size_t)k * D_ + jsb + n];
            *(_Float16*)((char*)Ulds + 32768 + byte_off)         = (_Float16)Us2[(size_t)k * D_ + jsb + n];
        }
    }
    __syncthreads();

    int rw = w * 16;              // wave's 16-row M tile
    int row0 = rw + lg * 4;       // this thread's 4 state rows (C-layout)
    float h[4] = {0.f, 0.f, 0.f, 0.f};

    unsigned int* fh = flags;
    unsigned int* fr = flags + NWG * 16;

    const char* Ub = (const char*)Ulds + lr * 1024;
    int swz = (lr & 7) << 4;

    for (int t = 0; t < T_; ++t) {
        int par = t & 1;
        _Float16* hmW = hmbuf + par * (64 * 512);
        _Float16* rhW = rhbuf + par * (64 * 512);

        // masked previous state; publish f16 copy for the all-gather
        float hm[4];
#pragma unroll
        for (int i = 0; i < 4; i++) {
            float m = 0.f;
            if (t > 0) m = (float)mask[(row0 + i) * T_ + (t - 1)];
            hm[i] = m * h[i];
            hmW[(row0 + i) * 512 + jsb + lr] = (_Float16)hm[i];
        }

        // prefetch xz/xr/xh for this step (independent of other WGs)
        const size_t stepoff = (size_t)t * 64 * 512;
        const _Float16* xz = xproj + stepoff;
        const _Float16* xr = xproj + (size_t)16777216 + stepoff;
        const _Float16* xh = xproj + (size_t)33554432 + stepoff;
        float xzv[4], xrv[4], xhv[4];
#pragma unroll
        for (int i = 0; i < 4; i++) {
            xzv[i] = (float)xz[(row0 + i) * 512 + jsb + lr];
            xrv[i] = (float)xr[(row0 + i) * 512 + jsb + lr];
            xhv[i] = (float)xh[(row0 + i) * 512 + jsb + lr];
        }

        // ---- barrier 1: hm visible everywhere ----
        __threadfence();
        __syncthreads();
        if (tid == 0)
            __hip_atomic_store(&fh[wg * 16], (unsigned int)(t + 1), __ATOMIC_RELEASE, __HIP_MEMORY_SCOPE_AGENT);
        if (w == 0) {
            for (;;) {
                unsigned int v = __hip_atomic_load(&fh[(l & (NWG - 1)) * 16], __ATOMIC_ACQUIRE, __HIP_MEMORY_SCOPE_AGENT);
                if (__all(v >= (unsigned int)(t + 1))) break;
                __builtin_amdgcn_s_sleep(1);
            }
        }
        __syncthreads();

        // ---- phase 1: z, r ----
        const _Float16* aRow = hmW + (size_t)(rw + lr) * 512 + lg * 8;
        half8 af[16];
#pragma unroll
        for (int kk = 0; kk < 16; kk++) af[kk] = *(const half8*)(aRow + kk * 32);
        floatx4 accz = {0.f, 0.f, 0.f, 0.f}, accr = {0.f, 0.f, 0.f, 0.f};
#pragma unroll
        for (int kk = 0; kk < 16; kk++) {
            int kbs = ((kk * 32 + lg * 8) * 2) ^ swz;
            half8 bz8 = *(const half8*)(Ub + kbs);
            half8 br8 = *(const half8*)(Ub + 16384 + kbs);
            accz = __builtin_amdgcn_mfma_f32_16x16x32_f16(af[kk], bz8, accz, 0, 0, 0);
            accr = __builtin_amdgcn_mfma_f32_16x16x32_f16(af[kk], br8, accr, 0, 0, 0);
        }
        float z4[4];
#pragma unroll
        for (int i = 0; i < 4; i++) {
            float zz = 1.f / (1.f + __expf(-(xzv[i] + accz[i])));
            float rr = 1.f / (1.f + __expf(-(xrv[i] + accr[i])));
            z4[i] = zz;
            float rh = rr * hm[i];
            rhW[(row0 + i) * 512 + jsb + lr] = (_Float16)rh;
        }

        // ---- barrier 2: r*hm visible everywhere ----
        __threadfence();
        __syncthreads();
        if (tid == 0)
            __hip_atomic_store(&fr[wg * 16], (unsigned int)(t + 1), __ATOMIC_RELEASE, __HIP_MEMORY_SCOPE_AGENT);
        if (w == 0) {
            for (;;) {
                unsigned int v = __hip_atomic_load(&fr[(l & (NWG - 1)) * 16], __ATOMIC_ACQUIRE, __HIP_MEMORY_SCOPE_AGENT);
                if (__all(v >= (unsigned int)(t + 1))) break;
                __builtin_amdgcn_s_sleep(1);
            }
        }
        __syncthreads();

        // ---- phase 2: candidate + state update ----
        const _Float16* aRow2 = rhW + (size_t)(rw + lr) * 512 + lg * 8;
        half8 af2[16];
#pragma unroll
        for (int kk = 0; kk < 16; kk++) af2[kk] = *(const half8*)(aRow2 + kk * 32);
        floatx4 acch = {0.f, 0.f, 0.f, 0.f};
#pragma unroll
        for (int kk = 0; kk < 16; kk++) {
            int kbs = ((kk * 32 + lg * 8) * 2) ^ swz;
            half8 bh8 = *(const half8*)(Ub + 32768 + kbs);
            acch = __builtin_amdgcn_mfma_f32_16x16x32_f16(af2[kk], bh8, acch, 0, 0, 0);
        }
#pragma unroll
        for (int i = 0; i < 4; i++) {
            float hh = tanhf(xhv[i] + acch[i]);
            h[i] = z4[i] * hm[i] + (1.f - z4[i]) * hh;
        }
    }

#pragma unroll
    for (int i = 0; i < 4; i++)
        out[(size_t)(row0 + i) * 512 + jsb + lr] = h[i];
}

extern "C" void kernel_launch(void* const* d_in, const int* in_sizes, int n_in,
                              void* d_out, int out_size, void* d_ws, size_t ws_size,
                              hipStream_t stream) {
    (void)in_sizes; (void)n_in; (void)out_size; (void)ws_size;
    const float* X  = (const float*)d_in[0];
    const float* Wz = (const float*)d_in[1];
    const float* Uz = (const float*)d_in[2];
    const float* bz = (const float*)d_in[3];
    const float* Wr = (const float*)d_in[4];
    const float* Ur = (const float*)d_in[5];
    const float* br = (const float*)d_in[6];
    const float* Wh = (const float*)d_in[7];
    const float* Uh = (const float*)d_in[8];
    const float* bh = (const float*)d_in[9];
    const int* mask = (const int*)d_in[10];
    float* out = (float*)d_out;

    char* ws = (char*)d_ws;
    unsigned int* flags = (unsigned int*)ws;                       // 4KB (2 flag arrays, 64B stride)
    _Float16* hmbuf = (_Float16*)(ws + 4096);                      // 128KB
    _Float16* rhbuf = (_Float16*)(ws + 4096 + 131072);             // 128KB
    _Float16* Xh    = (_Float16*)(ws + 4096 + 2 * 131072);         // 32MB
    _Float16* Wt    = (_Float16*)(ws + 4096 + 2 * 131072 + 33554432);           // 1.5MB
    _Float16* xproj = (_Float16*)(ws + 4096 + 2 * 131072 + 33554432 + 1572864); // 96MB

    hipMemsetAsync(flags, 0, 4096, stream);
    hipLaunchKernelGGL(k_cvtX, dim3(8192), dim3(256), 0, stream, X, Xh);
    hipLaunchKernelGGL(k_cvtW, dim3(8, 8, 3), dim3(256), 0, stream, Wz, Wr, Wh, Wt);
    hipLaunchKernelGGL(k_gemm, dim3(256, 4, 3), dim3(256), 0, stream, Xh, Wt, bz, br, bh, xproj);
    hipLaunchKernelGGL(k_scan, dim3(NWG), dim3(256), 0, stream, Uz, Ur, Uh, mask, xproj,
                       hmbuf, rhbuf, flags, out);
}

// Round 2
// 6290.683 us; speedup vs baseline: 1.5031x; 1.5031x over previous
//
#include <hip/hip_runtime.h>
#include <hip/hip_fp16.h>

#define B_   64
#define T_   512
#define DINc 512
#define D_   512
#define NWG  32
#define JS   16   // output columns per workgroup in scan

typedef _Float16 half8 __attribute__((ext_vector_type(8)));
typedef float   floatx4 __attribute__((ext_vector_type(4)));

// ---------------- X convert + transpose: Xh[m][k] = (f16) X[b][t][k], m = t*64+b ----------------
__global__ __launch_bounds__(256) void k_cvtX(const float* __restrict__ X, _Float16* __restrict__ Xh) {
    int idx = blockIdx.x * 256 + threadIdx.x;        // over 32768*64 groups of 8
    int m  = idx >> 6;
    int k8 = idx & 63;
    int b = m & 63, t = m >> 6;
    const float* src = X + ((size_t)(b * T_ + t)) * DINc + k8 * 8;
    float4 f0 = *(const float4*)(src);
    float4 f1 = *(const float4*)(src + 4);
    half8 h;
    h[0] = (_Float16)f0.x; h[1] = (_Float16)f0.y; h[2] = (_Float16)f0.z; h[3] = (_Float16)f0.w;
    h[4] = (_Float16)f1.x; h[5] = (_Float16)f1.y; h[6] = (_Float16)f1.z; h[7] = (_Float16)f1.w;
    *(half8*)(Xh + (size_t)m * DINc + k8 * 8) = h;
}

// ---------------- W transpose + convert: Wt[g][n][k] = (f16) W_g[k][n] ----------------
__global__ __launch_bounds__(256) void k_cvtW(const float* __restrict__ Wz, const float* __restrict__ Wr,
                                              const float* __restrict__ Wh, _Float16* __restrict__ Wt) {
    __shared__ float tile[64][65];
    int g = blockIdx.z;
    const float* W = (g == 0) ? Wz : ((g == 1) ? Wr : Wh);
    int n0 = blockIdx.x * 64, k0 = blockIdx.y * 64;
    int c = threadIdx.x & 63, r4 = threadIdx.x >> 6;
#pragma unroll
    for (int i = 0; i < 16; ++i) {
        int k = r4 + i * 4;
        tile[k][c] = W[(size_t)(k0 + k) * D_ + n0 + c];
    }
    __syncthreads();
    _Float16* out = Wt + (size_t)g * D_ * DINc;
#pragma unroll
    for (int i = 0; i < 16; ++i) {
        int n = r4 + i * 4;
        out[(size_t)(n0 + n) * DINc + k0 + c] = (_Float16)tile[c][n];
    }
}

// ---------------- input projections: xproj[g][m][n] = Xh[m][:] @ W_g[:][n] + b_g[n]  (f16 out) ----------------
__global__ __launch_bounds__(256) void k_gemm(const _Float16* __restrict__ Xh, const _Float16* __restrict__ Wt,
                                              const float* __restrict__ bz, const float* __restrict__ br,
                                              const float* __restrict__ bh, _Float16* __restrict__ xproj) {
    __shared__ _Float16 As[128 * 32];
    __shared__ _Float16 Bs[128 * 32];
    int g = blockIdx.z;
    const _Float16* Wg = Wt + (size_t)g * 512 * 512;
    const float* bias = (g == 0) ? bz : ((g == 1) ? br : bh);
    _Float16* out = xproj + (size_t)g * 32768 * 512;
    int mb = blockIdx.x * 128, nb = blockIdx.y * 128;
    int tid = threadIdx.x, l = tid & 63, w = tid >> 6;
    int wr = w >> 1, wc = w & 1;
    int lr = l & 15, lg = l >> 4;

    floatx4 acc[4][4] = {};

    int ga0 = tid, ga1 = tid + 256;       // 16B granules: row = ga>>2, gcol = ga&3
    int ra0 = ga0 >> 2, ca0 = (ga0 & 3) * 8;
    int ra1 = ga1 >> 2, ca1 = (ga1 & 3) * 8;

    uint4 pa0, pa1, pb0, pb1;
    pa0 = *(const uint4*)(Xh + (size_t)(mb + ra0) * 512 + ca0);
    pa1 = *(const uint4*)(Xh + (size_t)(mb + ra1) * 512 + ca1);
    pb0 = *(const uint4*)(Wg + (size_t)(nb + ra0) * 512 + ca0);
    pb1 = *(const uint4*)(Wg + (size_t)(nb + ra1) * 512 + ca1);

    for (int kt = 0; kt < 16; ++kt) {
        __syncthreads();
        *(uint4*)(&As[ga0 * 8]) = pa0;
        *(uint4*)(&As[ga1 * 8]) = pa1;
        *(uint4*)(&Bs[ga0 * 8]) = pb0;
        *(uint4*)(&Bs[ga1 * 8]) = pb1;
        __syncthreads();
        if (kt < 15) {
            int kb = (kt + 1) * 32;
            pa0 = *(const uint4*)(Xh + (size_t)(mb + ra0) * 512 + kb + ca0);
            pa1 = *(const uint4*)(Xh + (size_t)(mb + ra1) * 512 + kb + ca1);
            pb0 = *(const uint4*)(Wg + (size_t)(nb + ra0) * 512 + kb + ca0);
            pb1 = *(const uint4*)(Wg + (size_t)(nb + ra1) * 512 + kb + ca1);
        }
        half8 af[4], bf[4];
#pragma unroll
        for (int mi = 0; mi < 4; mi++) af[mi] = *(const half8*)(&As[(wr * 64 + mi * 16 + lr) * 32 + lg * 8]);
#pragma unroll
        for (int ni = 0; ni < 4; ni++) bf[ni] = *(const half8*)(&Bs[(wc * 64 + ni * 16 + lr) * 32 + lg * 8]);
#pragma unroll
        for (int mi = 0; mi < 4; mi++)
#pragma unroll
            for (int ni = 0; ni < 4; ni++)
                acc[mi][ni] = __builtin_amdgcn_mfma_f32_16x16x32_f16(af[mi], bf[ni], acc[mi][ni], 0, 0, 0);
    }

#pragma unroll
    for (int ni = 0; ni < 4; ni++) {
        int col = nb + wc * 64 + ni * 16 + lr;
        float bv = bias[col];
#pragma unroll
        for (int mi = 0; mi < 4; mi++) {
            int row = mb + wr * 64 + mi * 16 + lg * 4;
#pragma unroll
            for (int i = 0; i < 4; i++)
                out[(size_t)(row + i) * 512 + col] = (_Float16)(acc[mi][ni][i] + bv);
        }
    }
}

// -------- agent-scope (device-coherent, L2-bypassing) atomic helpers --------
__device__ __forceinline__ unsigned long long ld_agent(const unsigned long long* p) {
    return __hip_atomic_load(p, __ATOMIC_RELAXED, __HIP_MEMORY_SCOPE_AGENT);
}
__device__ __forceinline__ void st_agent(unsigned long long* p, unsigned long long v) {
    __hip_atomic_store(p, v, __ATOMIC_RELAXED, __HIP_MEMORY_SCOPE_AGENT);
}

// pack this thread's 4 fp32 values (4 rows, 1 col) into the 8B row-major unit
// (1 row, 4 cols) for its assigned row (lr&3), via 2-round shfl_xor butterfly
__device__ __forceinline__ unsigned long long pack_quad(const float v4[4], int lr) {
    unsigned long long unit = 0;
    int j = lr & 3;
#pragma unroll
    for (int i = 0; i < 4; i++) {
        _Float16 hv = (_Float16)v4[i];
        unsigned int v = (unsigned int)__builtin_bit_cast(unsigned short, hv);
        unsigned int o1 = __shfl_xor(v, 1, 64);
        unsigned int pair = (lr & 1) ? (o1 | (v << 16)) : (v | (o1 << 16));
        unsigned int q2 = __shfl_xor(pair, 2, 64);
        unsigned long long u = (lr & 2) ? ((unsigned long long)q2 | ((unsigned long long)pair << 32))
                                        : ((unsigned long long)pair | ((unsigned long long)q2 << 32));
        if (i == j) unit = u;
    }
    return unit;
}

// ---------------- recurrent scan: 32 persistent WGs, each owns JS=16 columns ----------------
__global__ __launch_bounds__(256) void k_scan(const float* __restrict__ Uz, const float* __restrict__ Ur,
                                              const float* __restrict__ Uh, const int* __restrict__ mask,
                                              const _Float16* __restrict__ xproj,
                                              unsigned long long* __restrict__ hmbuf,   // [2][64][512] f16, 8B units
                                              unsigned long long* __restrict__ rhbuf,   // [2][64][512] f16, 8B units
                                              unsigned int* __restrict__ flags,
                                              float* __restrict__ out) {
    __shared__ _Float16 Ulds[3 * JS * 512];   // 48KB: gate-major, transposed [n][k], XOR-swizzled
    int tid = threadIdx.x, l = tid & 63, w = tid >> 6;
    int lr = l & 15, lg = l >> 4;
    int wg = blockIdx.x;
    int jsb = wg * JS;

    // ---- stage U slices into LDS (transposed + swizzled), fp32 -> fp16 ----
    {
        const float* Us0 = Uz; const float* Us1 = Ur; const float* Us2 = Uh;
        for (int idx = tid; idx < JS * 512; idx += 256) {
            int n = idx & (JS - 1);
            int k = idx >> 4;
            int byte_off = n * 1024 + (((k * 2)) ^ ((n & 7) << 4));
            *(_Float16*)((char*)Ulds + byte_off)                 = (_Float16)Us0[(size_t)k * D_ + jsb + n];
            *(_Float16*)((char*)Ulds + 16384 + byte_off)         = (_Float16)Us1[(size_t)k * D_ + jsb + n];
            *(_Float16*)((char*)Ulds + 32768 + byte_off)         = (_Float16)Us2[(size_t)k * D_ + jsb + n];
        }
    }
    __syncthreads();

    int rw = w * 16;              // wave's 16-row M tile
    int row0 = rw + lg * 4;       // this thread's 4 state rows (C-layout)
    float h[4] = {0.f, 0.f, 0.f, 0.f};

    unsigned int* fh = flags;
    unsigned int* fr = flags + NWG * 16;

    const char* Ub = (const char*)Ulds + lr * 1024;
    int swz = (lr & 7) << 4;

    // publish-unit address pieces: row = row0 + (lr&3), colgroup = jsb/4 + (lr>>2)
    const int punit = (row0 + (lr & 3)) * 128 + (jsb >> 2) + ((lr >> 2) & 3);
    // gather base: row rw+lr, 8B-unit column offset lg*2
    const int gunit = (rw + lr) * 128 + lg * 2;

    for (int t = 0; t < T_; ++t) {
        int par = t & 1;
        unsigned long long* hmW = hmbuf + par * (64 * 512 / 4);
        unsigned long long* rhW = rhbuf + par * (64 * 512 / 4);

        // masked previous state; publish f16 packed copy for the all-gather
        float hm[4];
#pragma unroll
        for (int i = 0; i < 4; i++) {
            float m = 0.f;
            if (t > 0) m = (float)mask[(row0 + i) * T_ + (t - 1)];
            hm[i] = m * h[i];
        }
        st_agent(hmW + punit, pack_quad(hm, lr));

        // prefetch xz/xr/xh for this step (independent of other WGs; L2-warm)
        const size_t stepoff = (size_t)t * 64 * 512;
        const _Float16* xz = xproj + stepoff;
        const _Float16* xr = xproj + (size_t)16777216 + stepoff;
        const _Float16* xh = xproj + (size_t)33554432 + stepoff;
        float xzv[4], xrv[4], xhv[4];
#pragma unroll
        for (int i = 0; i < 4; i++) {
            xzv[i] = (float)xz[(row0 + i) * 512 + jsb + lr];
            xrv[i] = (float)xr[(row0 + i) * 512 + jsb + lr];
            xhv[i] = (float)xh[(row0 + i) * 512 + jsb + lr];
        }

        // ---- barrier 1: hm visible everywhere (no cache flush; sc1/IF coherent) ----
        asm volatile("s_waitcnt vmcnt(0)" ::: "memory");
        __syncthreads();
        if (tid == 0)
            __hip_atomic_store(&fh[wg * 16], (unsigned int)(t + 1), __ATOMIC_RELAXED, __HIP_MEMORY_SCOPE_AGENT);
        if (w == 0) {
            for (;;) {
                unsigned int v = __hip_atomic_load(&fh[(l & (NWG - 1)) * 16], __ATOMIC_RELAXED, __HIP_MEMORY_SCOPE_AGENT);
                if (__all(v >= (unsigned int)(t + 1))) break;
                __builtin_amdgcn_s_sleep(1);
            }
        }
        __syncthreads();

        // ---- phase 1: z, r ----
        half8 af[16];
#pragma unroll
        for (int kk = 0; kk < 16; kk++) {
            union { unsigned long long u[2]; half8 h8; } cv;
            cv.u[0] = ld_agent(hmW + gunit + kk * 8);
            cv.u[1] = ld_agent(hmW + gunit + kk * 8 + 1);
            af[kk] = cv.h8;
        }
        floatx4 accz = {0.f, 0.f, 0.f, 0.f}, accr = {0.f, 0.f, 0.f, 0.f};
#pragma unroll
        for (int kk = 0; kk < 16; kk++) {
            int kbs = ((kk * 32 + lg * 8) * 2) ^ swz;
            half8 bz8 = *(const half8*)(Ub + kbs);
            half8 br8 = *(const half8*)(Ub + 16384 + kbs);
            accz = __builtin_amdgcn_mfma_f32_16x16x32_f16(af[kk], bz8, accz, 0, 0, 0);
            accr = __builtin_amdgcn_mfma_f32_16x16x32_f16(af[kk], br8, accr, 0, 0, 0);
        }
        float z4[4], rh[4];
#pragma unroll
        for (int i = 0; i < 4; i++) {
            float zz = 1.f / (1.f + __expf(-(xzv[i] + accz[i])));
            float rr = 1.f / (1.f + __expf(-(xrv[i] + accr[i])));
            z4[i] = zz;
            rh[i] = rr * hm[i];
        }
        st_agent(rhW + punit, pack_quad(rh, lr));

        // ---- barrier 2: r*hm visible everywhere ----
        asm volatile("s_waitcnt vmcnt(0)" ::: "memory");
        __syncthreads();
        if (tid == 0)
            __hip_atomic_store(&fr[wg * 16], (unsigned int)(t + 1), __ATOMIC_RELAXED, __HIP_MEMORY_SCOPE_AGENT);
        if (w == 0) {
            for (;;) {
                unsigned int v = __hip_atomic_load(&fr[(l & (NWG - 1)) * 16], __ATOMIC_RELAXED, __HIP_MEMORY_SCOPE_AGENT);
                if (__all(v >= (unsigned int)(t + 1))) break;
                __builtin_amdgcn_s_sleep(1);
            }
        }
        __syncthreads();

        // ---- phase 2: candidate + state update ----
        half8 af2[16];
#pragma unroll
        for (int kk = 0; kk < 16; kk++) {
            union { unsigned long long u[2]; half8 h8; } cv;
            cv.u[0] = ld_agent(rhW + gunit + kk * 8);
            cv.u[1] = ld_agent(rhW + gunit + kk * 8 + 1);
            af2[kk] = cv.h8;
        }
        floatx4 acch = {0.f, 0.f, 0.f, 0.f};
#pragma unroll
        for (int kk = 0; kk < 16; kk++) {
            int kbs = ((kk * 32 + lg * 8) * 2) ^ swz;
            half8 bh8 = *(const half8*)(Ub + 32768 + kbs);
            acch = __builtin_amdgcn_mfma_f32_16x16x32_f16(af2[kk], bh8, acch, 0, 0, 0);
        }
#pragma unroll
        for (int i = 0; i < 4; i++) {
            float hh = tanhf(xhv[i] + acch[i]);
            h[i] = z4[i] * hm[i] + (1.f - z4[i]) * hh;
        }
    }

#pragma unroll
    for (int i = 0; i < 4; i++)
        out[(size_t)(row0 + i) * 512 + jsb + lr] = h[i];
}

extern "C" void kernel_launch(void* const* d_in, const int* in_sizes, int n_in,
                              void* d_out, int out_size, void* d_ws, size_t ws_size,
                              hipStream_t stream) {
    (void)in_sizes; (void)n_in; (void)out_size; (void)ws_size;
    const float* X  = (const float*)d_in[0];
    const float* Wz = (const float*)d_in[1];
    const float* Uz = (const float*)d_in[2];
    const float* bz = (const float*)d_in[3];
    const float* Wr = (const float*)d_in[4];
    const float* Ur = (const float*)d_in[5];
    const float* br = (const float*)d_in[6];
    const float* Wh = (const float*)d_in[7];
    const float* Uh = (const float*)d_in[8];
    const float* bh = (const float*)d_in[9];
    const int* mask = (const int*)d_in[10];
    float* out = (float*)d_out;

    char* ws = (char*)d_ws;
    unsigned int* flags = (unsigned int*)ws;                       // 4KB (2 flag arrays, 64B stride)
    unsigned long long* hmbuf = (unsigned long long*)(ws + 4096);  // 128KB
    unsigned long long* rhbuf = (unsigned long long*)(ws + 4096 + 131072);  // 128KB
    _Float16* Xh    = (_Float16*)(ws + 4096 + 2 * 131072);         // 32MB
    _Float16* Wt    = (_Float16*)(ws + 4096 + 2 * 131072 + 33554432);           // 1.5MB
    _Float16* xproj = (_Float16*)(ws + 4096 + 2 * 131072 + 33554432 + 1572864); // 96MB

    hipMemsetAsync(flags, 0, 4096, stream);
    hipLaunchKernelGGL(k_cvtX, dim3(8192), dim3(256), 0, stream, X, Xh);
    hipLaunchKernelGGL(k_cvtW, dim3(8, 8, 3), dim3(256), 0, stream, Wz, Wr, Wh, Wt);
    hipLaunchKernelGGL(k_gemm, dim3(256, 4, 3), dim3(256), 0, stream, Xh, Wt, bz, br, bh, xproj);
    hipLaunchKernelGGL(k_scan, dim3(NWG), dim3(256), 0, stream, Uz, Ur, Uh, mask, xproj,
                       hmbuf, rhbuf, flags, out);
}